// Round 4
// baseline (152.446 us; speedup 1.0000x reference)
//
#include <hip/hip_runtime.h>
#include <hip/hip_bf16.h>
#include <stdint.h>

// B=8192 triplet loss with hard-negative mining.
// prep: normalize -> bf16
// dist_topk: barrier-free, 32 rows/wave (A resident in 64 VGPR), B direct from
//            L1/L2, software-pipelined {issue loads -> mine prev acc -> MFMA},
//            top-5 via positive-float packed keys + v_max/v_med3 insert.
// merge_loss: merge 16 sorted runs, JAX threefry RNG, exact fp32 loss per row
// finalize: deterministic mean

#define NB 8192
#define NSPLIT 16
#define EPSF 1e-6f

typedef float f32x4 __attribute__((ext_vector_type(4)));
typedef short short8 __attribute__((ext_vector_type(8)));

struct U2 { uint32_t x, y; };

__host__ __device__ __forceinline__ uint32_t rotl32(uint32_t v, int n) {
  return (v << n) | (v >> (32 - n));
}

__host__ __device__ __forceinline__ U2 tf2x32(uint32_t k0, uint32_t k1,
                                              uint32_t x0, uint32_t x1) {
  uint32_t k2 = k0 ^ k1 ^ 0x1BD11BDAu;
#define TF_R(r) { x0 += x1; x1 = rotl32(x1, r); x1 ^= x0; }
  x0 += k0; x1 += k1;
  TF_R(13) TF_R(15) TF_R(26) TF_R(6)
  x0 += k1; x1 += k2 + 1u;
  TF_R(17) TF_R(29) TF_R(16) TF_R(24)
  x0 += k2; x1 += k0 + 2u;
  TF_R(13) TF_R(15) TF_R(26) TF_R(6)
  x0 += k0; x1 += k1 + 3u;
  TF_R(17) TF_R(29) TF_R(16) TF_R(24)
  x0 += k1; x1 += k2 + 4u;
  TF_R(13) TF_R(15) TF_R(26) TF_R(6)
  x0 += k2; x1 += k0 + 5u;
#undef TF_R
  U2 r; r.x = x0; r.y = x1; return r;
}

__device__ __forceinline__ uint32_t rng_word(U2 r) { return r.x ^ r.y; }

// u32 compare-and-swap (for the cold merge paths)
#define CAS2(A, B) { uint32_t _mx = (A) > (B) ? (A) : (B); \
                     uint32_t _mn = (A) > (B) ? (B) : (A); (A) = _mx; (B) = _mn; }
#define INS5(T0, T1, T2, T3, T4, C) { CAS2(T4, C); CAS2(T3, T4); CAS2(T2, T3); \
                                      CAS2(T1, T2); CAS2(T0, T1); }

// ---------------- prep: normalize -> bf16 ----------------
__global__ __launch_bounds__(256) void prep_kernel(
    const float* __restrict__ x,
    __hip_bfloat16* __restrict__ abf, __hip_bfloat16* __restrict__ pbf) {
  const int w = threadIdx.x >> 6, l = threadIdx.x & 63;
  const int row = blockIdx.x * 4 + w;
  const float4* xr = (const float4*)(x + (size_t)row * 512);
  const float4 a4 = xr[l];
  const float4 p4 = xr[64 + l];
  float sa = a4.x * a4.x + a4.y * a4.y + a4.z * a4.z + a4.w * a4.w;
  float sp = p4.x * p4.x + p4.y * p4.y + p4.z * p4.z + p4.w * p4.w;
#pragma unroll
  for (int off = 32; off; off >>= 1) { sa += __shfl_xor(sa, off); sp += __shfl_xor(sp, off); }
  const float ia = 1.0f / fmaxf(sqrtf(sa), 1e-12f);
  const float ip_ = 1.0f / fmaxf(sqrtf(sp), 1e-12f);
  ushort4 ua, up;
  ua.x = __builtin_bit_cast(unsigned short, __float2bfloat16(a4.x * ia));
  ua.y = __builtin_bit_cast(unsigned short, __float2bfloat16(a4.y * ia));
  ua.z = __builtin_bit_cast(unsigned short, __float2bfloat16(a4.z * ia));
  ua.w = __builtin_bit_cast(unsigned short, __float2bfloat16(a4.w * ia));
  up.x = __builtin_bit_cast(unsigned short, __float2bfloat16(p4.x * ip_));
  up.y = __builtin_bit_cast(unsigned short, __float2bfloat16(p4.y * ip_));
  up.z = __builtin_bit_cast(unsigned short, __float2bfloat16(p4.z * ip_));
  up.w = __builtin_bit_cast(unsigned short, __float2bfloat16(p4.w * ip_));
  *(ushort4*)((char*)abf + (size_t)row * 512 + l * 8) = ua;
  *(ushort4*)((char*)pbf + (size_t)row * 512 + l * 8) = up;
}

// ---------------- dist + per-row top-5 ----------------
// grid: 1024 blocks (XCD-rect swizzled), 256 thr = 4 waves; wave owns 32 rows
// x 512 cols. mfma(bF, aF): a-row (C col) = wrow + mi*16 + lo;
// p-col (C row) = colbase + g*16 + hi*4 + reg.
__global__ __launch_bounds__(256, 3) void dist_topk_kernel(
    const __hip_bfloat16* __restrict__ abf, const __hip_bfloat16* __restrict__ pbf,
    uint32_t* __restrict__ part) {
  __shared__ uint32_t mls[4][640]; // per-wave end-merge scratch (10 KB)

  const int tid = threadIdx.x;
  const int w = tid >> 6, l = tid & 63;
  const int lo = l & 15, hi = l >> 4;
  // XCD rect swizzle: xcd = b&7; each XCD gets 16 row-blocks x 8 splits
  // (A 1MB + B 2MB < 4MB L2/XCD).
  const int b = blockIdx.x;
  const int xcd = b & 7, jj = b >> 3;
  const int rb = (xcd & 3) * 16 + (jj & 15);  // row-block 0..63 (128 rows)
  const int sp = (xcd >> 2) * 8 + (jj >> 4);  // col-split 0..15 (512 cols)
  const int wrow = rb * 128 + w * 32;
  const int colbase = sp * 512;
  const bool hasDiag = (sp == (rb >> 2));

  // A resident: 32 rows x 256 k = 64 VGPR
  short8 aF[2][8];
#pragma unroll
  for (int mi = 0; mi < 2; ++mi)
#pragma unroll
    for (int kk = 0; kk < 8; ++kk)
      aF[mi][kk] = *(const short8*)((const char*)abf +
                     (size_t)(wrow + mi * 16 + lo) * 512 + kk * 64 + hi * 16);

  // top-5 state as positive-float packed keys (value-desc, idx-asc under >)
  float T[2][5];
#pragma unroll
  for (int mi = 0; mi < 2; ++mi)
#pragma unroll
    for (int q = 0; q < 5; ++q) T[mi][q] = 0.0f;

  const uint32_t vbase = 8191u - (uint32_t)colbase - (uint32_t)(hi * 4);
  const __hip_bfloat16* __restrict__ pb = pbf;

  short8 bF[8];
  f32x4 accA[2], accB[2];

#define LOADB(G)                                                            \
  {                                                                         \
    _Pragma("unroll")                                                       \
    for (int kk = 0; kk < 8; ++kk)                                          \
      bF[kk] = *(const short8*)((const char*)pb +                           \
                 (size_t)(colbase + (G) * 16 + lo) * 512 + kk * 64 + hi * 16); \
  }

#define MFMA_TO(ACC)                                                        \
  {                                                                         \
    _Pragma("unroll")                                                       \
    for (int mi = 0; mi < 2; ++mi) { f32x4 z = {0.f, 0.f, 0.f, 0.f}; ACC[mi] = z; } \
    _Pragma("unroll")                                                       \
    for (int kk = 0; kk < 8; ++kk) {                                        \
      ACC[0] = __builtin_amdgcn_mfma_f32_16x16x32_bf16(bF[kk], aF[0][kk], ACC[0], 0, 0, 0); \
      ACC[1] = __builtin_amdgcn_mfma_f32_16x16x32_bf16(bF[kk], aF[1][kk], ACC[1], 0, 0, 0); \
    }                                                                       \
  }

#define MINE(ACC, G)                                                        \
  {                                                                         \
    _Pragma("unroll")                                                       \
    for (int mi = 0; mi < 2; ++mi) {                                        \
      _Pragma("unroll")                                                     \
      for (int r = 0; r < 4; ++r) {                                         \
        uint32_t key = (__float_as_uint(ACC[mi][r] + 2.0f) & 0xFFFFE000u) | \
                       (vbase - (uint32_t)((G) * 16 + r));                  \
        if (hasDiag) {                                                      \
          if (colbase + (G) * 16 + hi * 4 + r == wrow + mi * 16 + lo) key = 0u; \
        }                                                                   \
        const float c = __uint_as_float(key);                               \
        const float t0 = T[mi][0], t1 = T[mi][1], t2 = T[mi][2],            \
                    t3 = T[mi][3], t4 = T[mi][4];                           \
        T[mi][0] = fmaxf(t0, c);                                            \
        T[mi][1] = __builtin_amdgcn_fmed3f(c, t0, t1);                      \
        T[mi][2] = __builtin_amdgcn_fmed3f(c, t1, t2);                      \
        T[mi][3] = __builtin_amdgcn_fmed3f(c, t2, t3);                      \
        T[mi][4] = __builtin_amdgcn_fmed3f(c, t3, t4);                      \
      }                                                                     \
    }                                                                       \
  }

  // software pipeline: issue loads(g) -> mine(acc of g-1) -> mfma(g)
  LOADB(0)
  MFMA_TO(accA)
#pragma unroll 1
  for (int it = 0; it < 15; ++it) {
    const int g1 = 2 * it + 1, g2 = 2 * it + 2;
    LOADB(g1) MINE(accA, g1 - 1) MFMA_TO(accB)
    LOADB(g2) MINE(accB, g2 - 1) MFMA_TO(accA)
  }
  LOADB(31) MINE(accA, 30) MFMA_TO(accB) MINE(accB, 31)

#undef LOADB
#undef MFMA_TO
#undef MINE

  // end-merge across the 4 hi-lanes of each row
#pragma unroll
  for (int mi = 0; mi < 2; ++mi)
#pragma unroll
    for (int q = 0; q < 5; ++q)
      mls[w][(mi * 16 + lo) * 20 + hi * 5 + q] = __float_as_uint(T[mi][q]);
  __syncthreads();
  if (l < 32) {
    uint32_t M0 = 0, M1 = 0, M2 = 0, M3 = 0, M4 = 0;
#pragma unroll
    for (int q = 0; q < 20; ++q) {
      uint32_t c = mls[w][l * 20 + q];
      INS5(M0, M1, M2, M3, M4, c);
    }
    const int row = wrow + l;
    uint32_t* dst = part + ((size_t)row * NSPLIT + sp) * 5;
    dst[0] = M0; dst[1] = M1; dst[2] = M2; dst[3] = M3; dst[4] = M4;
  }
}

// ---------------- merge splits + RNG + exact fp32 loss ----------------
__global__ __launch_bounds__(64) void merge_loss_kernel(
    const float* __restrict__ x, const uint32_t* __restrict__ part,
    float* __restrict__ rowloss,
    uint32_t k1a, uint32_t k1b, uint32_t k2a, uint32_t k2b) {
  const int i = blockIdx.x, l = threadIdx.x;
  __shared__ uint32_t cs[80];
  const uint32_t* src = part + (size_t)i * (NSPLIT * 5);
  cs[l] = src[l];
  if (l < 16) cs[64 + l] = src[64 + l];
  __syncthreads();

  uint32_t T0 = 0, T1 = 0, T2 = 0, T3 = 0, T4 = 0;
  for (int rch = 0; rch < 16; ++rch) {
    for (int q = 0; q < 5; ++q) {      // runs sorted desc -> early out (uniform)
      uint32_t c = cs[rch * 5 + q];
      if (c <= T4) break;
      INS5(T0, T1, T2, T3, T4, c);
    }
  }

  // RNG: coin = uniform(k1) < 0.5 <=> MSB==0 ; randint(k2,0,5)
  const uint32_t cw = rng_word(tf2x32(k1a, k1b, 0u, (uint32_t)i));
  const bool coin = (cw >> 31) == 0u;
  const uint32_t hb = rng_word(tf2x32(k2a, k2b, 0u, (uint32_t)i));
  const uint32_t lb = rng_word(tf2x32(k2a, k2b, 0u, (uint32_t)(NB + i)));
  const int rr = (int)(((hb % 5u) + (lb % 5u)) % 5u);
  const int rank = coin ? 0 : rr;
  const uint32_t kch = (rank == 0) ? T0 : (rank == 1) ? T1 : (rank == 2) ? T2
                     : (rank == 3) ? T3 : T4;
  const int neg = 8191 - (int)(kch & 8191u);

  // exact fp32 loss from raw x
  const float4 xa = *(const float4*)(x + (size_t)i * 512 + l * 4);
  const float4 xp = *(const float4*)(x + (size_t)i * 512 + 256 + l * 4);
  const float4 xn = *(const float4*)(x + (size_t)neg * 512 + 256 + l * 4);
  float sa = xa.x * xa.x + xa.y * xa.y + xa.z * xa.z + xa.w * xa.w;
  float sp = xp.x * xp.x + xp.y * xp.y + xp.z * xp.z + xp.w * xp.w;
  float sn = xn.x * xn.x + xn.y * xn.y + xn.z * xn.z + xn.w * xn.w;
#pragma unroll
  for (int off = 32; off; off >>= 1) {
    sa += __shfl_xor(sa, off); sp += __shfl_xor(sp, off); sn += __shfl_xor(sn, off);
  }
  const float na = fmaxf(sqrtf(sa), 1e-12f);
  const float np = fmaxf(sqrtf(sp), 1e-12f);
  const float nn = fmaxf(sqrtf(sn), 1e-12f);

  float pos = 0.f, ng = 0.f;
  {
    float av, pv, nv, dp, dn;
    av = xa.x / na; pv = xp.x / np; nv = xn.x / nn;
    dp = av - pv + EPSF; pos += dp * dp; dn = av - nv + EPSF; ng += dn * dn;
    av = xa.y / na; pv = xp.y / np; nv = xn.y / nn;
    dp = av - pv + EPSF; pos += dp * dp; dn = av - nv + EPSF; ng += dn * dn;
    av = xa.z / na; pv = xp.z / np; nv = xn.z / nn;
    dp = av - pv + EPSF; pos += dp * dp; dn = av - nv + EPSF; ng += dn * dn;
    av = xa.w / na; pv = xp.w / np; nv = xn.w / nn;
    dp = av - pv + EPSF; pos += dp * dp; dn = av - nv + EPSF; ng += dn * dn;
  }
#pragma unroll
  for (int off = 32; off; off >>= 1) {
    pos += __shfl_xor(pos, off); ng += __shfl_xor(ng, off);
  }
  if (l == 0) rowloss[i] = fmaxf(pos - ng, 0.0f);
}

// ---------------- deterministic mean ----------------
__global__ __launch_bounds__(256) void finalize_kernel(
    const float* __restrict__ rowloss, float* __restrict__ out) {
  __shared__ float s[256];
  const int t = threadIdx.x;
  float a = 0.f;
  for (int k = 0; k < NB / 256; ++k) a += rowloss[t + 256 * k];
  s[t] = a;
  __syncthreads();
  for (int h = 128; h; h >>= 1) {
    if (t < h) s[t] += s[t + h];
    __syncthreads();
  }
  if (t == 0) out[0] = s[0] / (float)NB;
}

extern "C" void kernel_launch(void* const* d_in, const int* in_sizes, int n_in,
                              void* d_out, int out_size, void* d_ws, size_t ws_size,
                              hipStream_t stream) {
  (void)in_sizes; (void)n_in; (void)out_size; (void)ws_size;
  const float* x = (const float*)d_in[0];
  float* out = (float*)d_out;
  char* ws = (char*)d_ws;

  __hip_bfloat16* abf = (__hip_bfloat16*)(ws);                            // 4 MB
  __hip_bfloat16* pbf = (__hip_bfloat16*)(ws + (size_t)4 * 1024 * 1024);  // 4 MB
  uint32_t* part = (uint32_t*)(ws + (size_t)8 * 1024 * 1024);             // 2.62 MB
  float* rowloss = (float*)(ws + (size_t)8 * 1024 * 1024 +
                            (size_t)NB * NSPLIT * 5 * sizeof(uint32_t));  // 32 KB

  // JAX: kr = key(1); k1, k2 = split(kr)  (threefry partitionable)
  U2 c0 = tf2x32(0u, 1u, 0u, 0u);
  U2 c1 = tf2x32(0u, 1u, 0u, 1u);
  const uint32_t k1a = c0.x, k1b = c0.y;
  const uint32_t k2a = c1.x, k2b = c1.y;

  prep_kernel<<<NB / 4, 256, 0, stream>>>(x, abf, pbf);
  dist_topk_kernel<<<1024, 256, 0, stream>>>(abf, pbf, part);
  merge_loss_kernel<<<NB, 64, 0, stream>>>(x, part, rowloss, k1a, k1b, k2a, k2b);
  finalize_kernel<<<1, 256, 0, stream>>>(rowloss, out);
}

// Round 5
// 95.536 us; speedup vs baseline: 1.5957x; 1.5957x over previous
//
#include <hip/hip_runtime.h>
#include <hip/hip_bf16.h>
#include <stdint.h>

// B=8192 triplet loss with hard-negative mining.
// prep: normalize -> bf16
// dist_topk: barrier-free, 64 rows/wave; A pinned in 128 VGPR via opaque asm
//            fence (defeats remat — R4's VGPR=80 collapse), B direct from
//            L1/L2, pipeline {load g -> mine g-1 -> mfma g},
//            top-5 via positive-float packed keys + v_max/v_med3 insert.
// merge_loss: merge 16 sorted runs, JAX threefry RNG, exact fp32 loss per row
// finalize: deterministic mean

#define NB 8192
#define NSPLIT 16
#define EPSF 1e-6f

typedef float f32x4 __attribute__((ext_vector_type(4)));
typedef short short8 __attribute__((ext_vector_type(8)));

struct U2 { uint32_t x, y; };

__host__ __device__ __forceinline__ uint32_t rotl32(uint32_t v, int n) {
  return (v << n) | (v >> (32 - n));
}

__host__ __device__ __forceinline__ U2 tf2x32(uint32_t k0, uint32_t k1,
                                              uint32_t x0, uint32_t x1) {
  uint32_t k2 = k0 ^ k1 ^ 0x1BD11BDAu;
#define TF_R(r) { x0 += x1; x1 = rotl32(x1, r); x1 ^= x0; }
  x0 += k0; x1 += k1;
  TF_R(13) TF_R(15) TF_R(26) TF_R(6)
  x0 += k1; x1 += k2 + 1u;
  TF_R(17) TF_R(29) TF_R(16) TF_R(24)
  x0 += k2; x1 += k0 + 2u;
  TF_R(13) TF_R(15) TF_R(26) TF_R(6)
  x0 += k0; x1 += k1 + 3u;
  TF_R(17) TF_R(29) TF_R(16) TF_R(24)
  x0 += k1; x1 += k2 + 4u;
  TF_R(13) TF_R(15) TF_R(26) TF_R(6)
  x0 += k2; x1 += k0 + 5u;
#undef TF_R
  U2 r; r.x = x0; r.y = x1; return r;
}

__device__ __forceinline__ uint32_t rng_word(U2 r) { return r.x ^ r.y; }

// u32 compare-and-swap (cold merge paths)
#define CAS2(A, B) { uint32_t _mx = (A) > (B) ? (A) : (B); \
                     uint32_t _mn = (A) > (B) ? (B) : (A); (A) = _mx; (B) = _mn; }
#define INS5(T0, T1, T2, T3, T4, C) { CAS2(T4, C); CAS2(T3, T4); CAS2(T2, T3); \
                                      CAS2(T1, T2); CAS2(T0, T1); }

// ---------------- prep: normalize -> bf16 ----------------
__global__ __launch_bounds__(256) void prep_kernel(
    const float* __restrict__ x,
    __hip_bfloat16* __restrict__ abf, __hip_bfloat16* __restrict__ pbf) {
  const int w = threadIdx.x >> 6, l = threadIdx.x & 63;
  const int row = blockIdx.x * 4 + w;
  const float4* xr = (const float4*)(x + (size_t)row * 512);
  const float4 a4 = xr[l];
  const float4 p4 = xr[64 + l];
  float sa = a4.x * a4.x + a4.y * a4.y + a4.z * a4.z + a4.w * a4.w;
  float sp = p4.x * p4.x + p4.y * p4.y + p4.z * p4.z + p4.w * p4.w;
#pragma unroll
  for (int off = 32; off; off >>= 1) { sa += __shfl_xor(sa, off); sp += __shfl_xor(sp, off); }
  const float ia = 1.0f / fmaxf(sqrtf(sa), 1e-12f);
  const float ip_ = 1.0f / fmaxf(sqrtf(sp), 1e-12f);
  ushort4 ua, up;
  ua.x = __builtin_bit_cast(unsigned short, __float2bfloat16(a4.x * ia));
  ua.y = __builtin_bit_cast(unsigned short, __float2bfloat16(a4.y * ia));
  ua.z = __builtin_bit_cast(unsigned short, __float2bfloat16(a4.z * ia));
  ua.w = __builtin_bit_cast(unsigned short, __float2bfloat16(a4.w * ia));
  up.x = __builtin_bit_cast(unsigned short, __float2bfloat16(p4.x * ip_));
  up.y = __builtin_bit_cast(unsigned short, __float2bfloat16(p4.y * ip_));
  up.z = __builtin_bit_cast(unsigned short, __float2bfloat16(p4.z * ip_));
  up.w = __builtin_bit_cast(unsigned short, __float2bfloat16(p4.w * ip_));
  *(ushort4*)((char*)abf + (size_t)row * 512 + l * 8) = ua;
  *(ushort4*)((char*)pbf + (size_t)row * 512 + l * 8) = up;
}

// ---------------- dist + per-row top-5 ----------------
// grid: 512 blocks (XCD-rect swizzled), 256 thr = 4 waves; wave owns 64 rows
// x 512 cols. mfma(bF, aF): a-row (C col) = wrow + mi*16 + lo;
// p-col (C row) = colbase + g*16 + hi*4 + reg.
__global__ __launch_bounds__(256, 2) void dist_topk_kernel(
    const __hip_bfloat16* __restrict__ abf, const __hip_bfloat16* __restrict__ pbf,
    uint32_t* __restrict__ part) {
  __shared__ uint32_t mls[4][1280]; // per-wave end-merge scratch (20 KB)

  const int tid = threadIdx.x;
  const int w = tid >> 6, l = tid & 63;
  const int lo = l & 15, hi = l >> 4;
  // XCD rect swizzle: xcd = b&7; each XCD gets 8 row-blocks x 8 splits
  // (A 1MB + B 2MB < 4MB L2/XCD).
  const int b = blockIdx.x;
  const int xcd = b & 7, jj = b >> 3;
  const int xb = (xcd & 3) * 8 + (jj & 7);   // row-block 0..31 (256 rows)
  const int sp = (xcd >> 2) * 8 + (jj >> 3); // col-split 0..15 (512 cols)
  const int wrow = xb * 256 + w * 64;
  const int colbase = sp * 512;
  const bool hasDiag = (sp == (xb >> 1));

  // A resident: 64 rows x 256 k = 128 VGPR, pinned with an opaque asm fence
  // so the allocator cannot rematerialize the loads inside the loop (R4 bug).
  f32x4 aF[4][8];
#pragma unroll
  for (int mi = 0; mi < 4; ++mi)
#pragma unroll
    for (int kk = 0; kk < 8; ++kk)
      aF[mi][kk] = *(const f32x4*)((const char*)abf +
                     (size_t)(wrow + mi * 16 + lo) * 512 + kk * 64 + hi * 16);
#pragma unroll
  for (int mi = 0; mi < 4; ++mi)
#pragma unroll
    for (int kk = 0; kk < 8; ++kk)
      asm volatile("" : "+v"(aF[mi][kk]));

  // top-5 state as positive-float packed keys (value-desc, idx-asc under >)
  float T[4][5];
#pragma unroll
  for (int mi = 0; mi < 4; ++mi)
#pragma unroll
    for (int q = 0; q < 5; ++q) T[mi][q] = 0.0f;

  const uint32_t vbase = 8191u - (uint32_t)colbase - (uint32_t)(hi * 4);
  const __hip_bfloat16* __restrict__ pb = pbf;

  short8 bF[8];
  f32x4 accA[4], accB[4];

#define LOADB(G)                                                            \
  {                                                                         \
    _Pragma("unroll")                                                       \
    for (int kk = 0; kk < 8; ++kk)                                          \
      bF[kk] = *(const short8*)((const char*)pb +                           \
                 (size_t)(colbase + (G) * 16 + lo) * 512 + kk * 64 + hi * 16); \
  }

#define MFMA_TO(ACC)                                                        \
  {                                                                         \
    _Pragma("unroll")                                                       \
    for (int mi = 0; mi < 4; ++mi) { f32x4 z = {0.f, 0.f, 0.f, 0.f}; ACC[mi] = z; } \
    _Pragma("unroll")                                                       \
    for (int kk = 0; kk < 8; ++kk) {                                        \
      _Pragma("unroll")                                                     \
      for (int mi = 0; mi < 4; ++mi)                                        \
        ACC[mi] = __builtin_amdgcn_mfma_f32_16x16x32_bf16(                  \
            bF[kk], __builtin_bit_cast(short8, aF[mi][kk]), ACC[mi], 0, 0, 0); \
    }                                                                       \
  }

#define MINE(ACC, G)                                                        \
  {                                                                         \
    _Pragma("unroll")                                                       \
    for (int mi = 0; mi < 4; ++mi) {                                        \
      _Pragma("unroll")                                                     \
      for (int r = 0; r < 4; ++r) {                                         \
        uint32_t key = (__float_as_uint(ACC[mi][r] + 2.0f) & 0xFFFFE000u) | \
                       (vbase - (uint32_t)((G) * 16 + r));                  \
        if (hasDiag) {                                                      \
          if (colbase + (G) * 16 + hi * 4 + r == wrow + mi * 16 + lo) key = 0u; \
        }                                                                   \
        const float c = __uint_as_float(key);                               \
        const float t0 = T[mi][0], t1 = T[mi][1], t2 = T[mi][2],            \
                    t3 = T[mi][3], t4 = T[mi][4];                           \
        T[mi][0] = fmaxf(t0, c);                                            \
        T[mi][1] = __builtin_amdgcn_fmed3f(c, t0, t1);                      \
        T[mi][2] = __builtin_amdgcn_fmed3f(c, t1, t2);                      \
        T[mi][3] = __builtin_amdgcn_fmed3f(c, t2, t3);                      \
        T[mi][4] = __builtin_amdgcn_fmed3f(c, t3, t4);                      \
      }                                                                     \
    }                                                                       \
  }

  // software pipeline: issue loads(g) -> mine(acc of g-1) -> mfma(g)
  LOADB(0)
  MFMA_TO(accA)
#pragma unroll 1
  for (int it = 0; it < 15; ++it) {
    const int g1 = 2 * it + 1, g2 = 2 * it + 2;
    LOADB(g1) MINE(accA, g1 - 1) MFMA_TO(accB)
    LOADB(g2) MINE(accB, g2 - 1) MFMA_TO(accA)
  }
  LOADB(31) MINE(accA, 30) MFMA_TO(accB) MINE(accB, 31)

#undef LOADB
#undef MFMA_TO
#undef MINE

  // end-merge across the 4 hi-lanes of each row (lane l merges row wrow+l)
#pragma unroll
  for (int mi = 0; mi < 4; ++mi)
#pragma unroll
    for (int q = 0; q < 5; ++q)
      mls[w][(mi * 16 + lo) * 20 + hi * 5 + q] = __float_as_uint(T[mi][q]);
  __syncthreads();
  {
    uint32_t M0 = 0, M1 = 0, M2 = 0, M3 = 0, M4 = 0;
#pragma unroll
    for (int q = 0; q < 20; ++q) {
      uint32_t c = mls[w][l * 20 + q];
      INS5(M0, M1, M2, M3, M4, c);
    }
    const int row = wrow + l;
    uint32_t* dst = part + ((size_t)row * NSPLIT + sp) * 5;
    dst[0] = M0; dst[1] = M1; dst[2] = M2; dst[3] = M3; dst[4] = M4;
  }
}

// ---------------- merge splits + RNG + exact fp32 loss ----------------
__global__ __launch_bounds__(64) void merge_loss_kernel(
    const float* __restrict__ x, const uint32_t* __restrict__ part,
    float* __restrict__ rowloss,
    uint32_t k1a, uint32_t k1b, uint32_t k2a, uint32_t k2b) {
  const int i = blockIdx.x, l = threadIdx.x;
  __shared__ uint32_t cs[80];
  const uint32_t* src = part + (size_t)i * (NSPLIT * 5);
  cs[l] = src[l];
  if (l < 16) cs[64 + l] = src[64 + l];
  __syncthreads();

  uint32_t T0 = 0, T1 = 0, T2 = 0, T3 = 0, T4 = 0;
  for (int rch = 0; rch < 16; ++rch) {
    for (int q = 0; q < 5; ++q) {      // runs sorted desc -> early out (uniform)
      uint32_t c = cs[rch * 5 + q];
      if (c <= T4) break;
      INS5(T0, T1, T2, T3, T4, c);
    }
  }

  // RNG: coin = uniform(k1) < 0.5 <=> MSB==0 ; randint(k2,0,5)
  const uint32_t cw = rng_word(tf2x32(k1a, k1b, 0u, (uint32_t)i));
  const bool coin = (cw >> 31) == 0u;
  const uint32_t hb = rng_word(tf2x32(k2a, k2b, 0u, (uint32_t)i));
  const uint32_t lb = rng_word(tf2x32(k2a, k2b, 0u, (uint32_t)(NB + i)));
  const int rr = (int)(((hb % 5u) + (lb % 5u)) % 5u);
  const int rank = coin ? 0 : rr;
  const uint32_t kch = (rank == 0) ? T0 : (rank == 1) ? T1 : (rank == 2) ? T2
                     : (rank == 3) ? T3 : T4;
  const int neg = 8191 - (int)(kch & 8191u);

  // exact fp32 loss from raw x
  const float4 xa = *(const float4*)(x + (size_t)i * 512 + l * 4);
  const float4 xp = *(const float4*)(x + (size_t)i * 512 + 256 + l * 4);
  const float4 xn = *(const float4*)(x + (size_t)neg * 512 + 256 + l * 4);
  float sa = xa.x * xa.x + xa.y * xa.y + xa.z * xa.z + xa.w * xa.w;
  float sp = xp.x * xp.x + xp.y * xp.y + xp.z * xp.z + xp.w * xp.w;
  float sn = xn.x * xn.x + xn.y * xn.y + xn.z * xn.z + xn.w * xn.w;
#pragma unroll
  for (int off = 32; off; off >>= 1) {
    sa += __shfl_xor(sa, off); sp += __shfl_xor(sp, off); sn += __shfl_xor(sn, off);
  }
  const float na = fmaxf(sqrtf(sa), 1e-12f);
  const float np = fmaxf(sqrtf(sp), 1e-12f);
  const float nn = fmaxf(sqrtf(sn), 1e-12f);

  float pos = 0.f, ng = 0.f;
  {
    float av, pv, nv, dp, dn;
    av = xa.x / na; pv = xp.x / np; nv = xn.x / nn;
    dp = av - pv + EPSF; pos += dp * dp; dn = av - nv + EPSF; ng += dn * dn;
    av = xa.y / na; pv = xp.y / np; nv = xn.y / nn;
    dp = av - pv + EPSF; pos += dp * dp; dn = av - nv + EPSF; ng += dn * dn;
    av = xa.z / na; pv = xp.z / np; nv = xn.z / nn;
    dp = av - pv + EPSF; pos += dp * dp; dn = av - nv + EPSF; ng += dn * dn;
    av = xa.w / na; pv = xp.w / np; nv = xn.w / nn;
    dp = av - pv + EPSF; pos += dp * dp; dn = av - nv + EPSF; ng += dn * dn;
  }
#pragma unroll
  for (int off = 32; off; off >>= 1) {
    pos += __shfl_xor(pos, off); ng += __shfl_xor(ng, off);
  }
  if (l == 0) rowloss[i] = fmaxf(pos - ng, 0.0f);
}

// ---------------- deterministic mean ----------------
__global__ __launch_bounds__(256) void finalize_kernel(
    const float* __restrict__ rowloss, float* __restrict__ out) {
  __shared__ float s[256];
  const int t = threadIdx.x;
  float a = 0.f;
  for (int k = 0; k < NB / 256; ++k) a += rowloss[t + 256 * k];
  s[t] = a;
  __syncthreads();
  for (int h = 128; h; h >>= 1) {
    if (t < h) s[t] += s[t + h];
    __syncthreads();
  }
  if (t == 0) out[0] = s[0] / (float)NB;
}

extern "C" void kernel_launch(void* const* d_in, const int* in_sizes, int n_in,
                              void* d_out, int out_size, void* d_ws, size_t ws_size,
                              hipStream_t stream) {
  (void)in_sizes; (void)n_in; (void)out_size; (void)ws_size;
  const float* x = (const float*)d_in[0];
  float* out = (float*)d_out;
  char* ws = (char*)d_ws;

  __hip_bfloat16* abf = (__hip_bfloat16*)(ws);                            // 4 MB
  __hip_bfloat16* pbf = (__hip_bfloat16*)(ws + (size_t)4 * 1024 * 1024);  // 4 MB
  uint32_t* part = (uint32_t*)(ws + (size_t)8 * 1024 * 1024);             // 2.62 MB
  float* rowloss = (float*)(ws + (size_t)8 * 1024 * 1024 +
                            (size_t)NB * NSPLIT * 5 * sizeof(uint32_t));  // 32 KB

  // JAX: kr = key(1); k1, k2 = split(kr)  (threefry partitionable)
  U2 c0 = tf2x32(0u, 1u, 0u, 0u);
  U2 c1 = tf2x32(0u, 1u, 0u, 1u);
  const uint32_t k1a = c0.x, k1b = c0.y;
  const uint32_t k2a = c1.x, k2b = c1.y;

  prep_kernel<<<NB / 4, 256, 0, stream>>>(x, abf, pbf);
  dist_topk_kernel<<<512, 256, 0, stream>>>(abf, pbf, part);
  merge_loss_kernel<<<NB, 64, 0, stream>>>(x, part, rowloss, k1a, k1b, k2a, k2b);
  finalize_kernel<<<1, 256, 0, stream>>>(rowloss, out);
}